// Round 2
// baseline (972.557 us; speedup 1.0000x reference)
//
#include <hip/hip_runtime.h>
#include <cstddef>

// Problem constants (fixed by setup_inputs)
#define B_  4
#define L_  1024
#define H_  8
#define DK_ 32
#define DV_ 32
#define BH_ 32            // B_*H_
#define HD_ 256           // H_*DK_

// Kernel A: one block per i. Threads: bh = tid>>3 (32), jl = tid&7 (8).
// Writes u = exp(score/T) (unnormalized) into the attn output region.
__global__ __launch_bounds__(256) void score_kernel(
    const float* __restrict__ q,
    const float* __restrict__ k,
    const float* __restrict__ a_k,
    float* __restrict__ attn_u)
{
    const float INV_T = 0.17677669529663687f;  // 1/sqrt(32)
    const int i   = blockIdx.x;
    const int tid = threadIdx.x;
    const int bh  = tid >> 3;
    const int jl  = tid & 7;
    const int b   = bh >> 3;
    const int h   = bh & 7;

    // a_k chunk, padded to 33 to break d-index bank conflicts
    __shared__ float a_s[64][33];

    // k[b, i, h*32 + d] -> registers
    float kf[DK_];
    {
        const float* kp = k + (((size_t)b * L_ + i) * HD_ + h * DK_);
        #pragma unroll
        for (int d = 0; d < DK_; d += 4) {
            float4 kv = *reinterpret_cast<const float4*>(kp + d);
            kf[d + 0] = kv.x; kf[d + 1] = kv.y; kf[d + 2] = kv.z; kf[d + 3] = kv.w;
        }
    }

    const float* arow = a_k + (size_t)i * L_ * DK_;
    float* urow = attn_u + ((size_t)bh * L_ + i) * L_;

    for (int j0 = 0; j0 < L_; j0 += 64) {
        __syncthreads();   // protect a_s from previous iteration's readers
        {
            // stage 64 x 32 floats -> LDS; 2048 elems, 8 per thread
            const int g  = tid * 8;
            const int jj = g >> 5;
            const int dd = g & 31;
            const float* ap = arow + (size_t)(j0 + jj) * DK_ + dd;
            float4 a0 = *reinterpret_cast<const float4*>(ap);
            float4 a1 = *reinterpret_cast<const float4*>(ap + 4);
            a_s[jj][dd + 0] = a0.x; a_s[jj][dd + 1] = a0.y;
            a_s[jj][dd + 2] = a0.z; a_s[jj][dd + 3] = a0.w;
            a_s[jj][dd + 4] = a1.x; a_s[jj][dd + 5] = a1.y;
            a_s[jj][dd + 6] = a1.z; a_s[jj][dd + 7] = a1.w;
        }
        __syncthreads();

        float st[8];
        #pragma unroll
        for (int r = 0; r < 8; ++r) {
            const int jj = jl * 8 + r;
            const int j  = j0 + jj;
            const float* qp = q + (((size_t)b * L_ + j) * HD_ + h * DK_);
            float s = 0.f;
            #pragma unroll
            for (int dd = 0; dd < DK_; dd += 4) {
                float4 qv = *reinterpret_cast<const float4*>(qp + dd);
                s = fmaf(kf[dd + 0] * a_s[jj][dd + 0], qv.x, s);
                s = fmaf(kf[dd + 1] * a_s[jj][dd + 1], qv.y, s);
                s = fmaf(kf[dd + 2] * a_s[jj][dd + 2], qv.z, s);
                s = fmaf(kf[dd + 3] * a_s[jj][dd + 3], qv.w, s);
            }
            st[r] = __expf(s * INV_T);
        }
        float* wp = urow + j0 + jl * 8;
        *reinterpret_cast<float4*>(wp)     = make_float4(st[0], st[1], st[2], st[3]);
        *reinterpret_cast<float4*>(wp + 4) = make_float4(st[4], st[5], st[6], st[7]);
    }
}

// Kernel B: one block per row (bh,i). Normalizes attn in place and computes out.
__global__ __launch_bounds__(256) void finish_kernel(
    const float* __restrict__ v,
    float* __restrict__ attn,   // holds u on entry, p on exit
    float* __restrict__ out)
{
    const int row = blockIdx.x;          // bh*1024 + i
    const int bh  = row >> 10;
    const int i   = row & 1023;
    const int b   = bh >> 3;
    const int h   = bh & 7;
    const int tid = threadIdx.x;

    __shared__ float s_u[L_];
    __shared__ float s_part[8][32];
    __shared__ float s_red[4];
    __shared__ float s_inv;

    float* urow = attn + (size_t)row * L_;

    // load 4 u's per thread, stash to LDS, partial row sum
    const int j4 = tid * 4;
    float4 uv = *reinterpret_cast<const float4*>(urow + j4);
    s_u[j4 + 0] = uv.x; s_u[j4 + 1] = uv.y;
    s_u[j4 + 2] = uv.z; s_u[j4 + 3] = uv.w;
    float lp = uv.x + uv.y + uv.z + uv.w;
    // wave(64) reduce then cross-wave via LDS
    #pragma unroll
    for (int off = 32; off > 0; off >>= 1) lp += __shfl_down(lp, off);
    if ((tid & 63) == 0) s_red[tid >> 6] = lp;
    __syncthreads();
    if (tid == 0) s_inv = 1.0f / (s_red[0] + s_red[1] + s_red[2] + s_red[3]);
    __syncthreads();
    const float inv = s_inv;

    // write normalized p back (coalesced 16B per thread)
    *reinterpret_cast<float4*>(urow + j4) =
        make_float4(uv.x * inv, uv.y * inv, uv.z * inv, uv.w * inv);

    // PV: thread = (jg, d); out[bh,i,d] = inv * sum_j u[j] * v[b,j,h*32+d]
    const int d  = tid & 31;
    const int jg = tid >> 5;            // 8 groups of 128 j
    const float* vp = v + (size_t)b * L_ * HD_ + h * DV_ + d;
    float acc = 0.f;
    const int jbase = jg * 128;
    #pragma unroll 4
    for (int jj = 0; jj < 128; ++jj) {
        const int j = jbase + jj;
        acc = fmaf(s_u[j], vp[(size_t)j * HD_], acc);
    }
    s_part[jg][d] = acc;
    __syncthreads();
    if (tid < 32) {
        float o = 0.f;
        #pragma unroll
        for (int g = 0; g < 8; ++g) o += s_part[g][tid];
        out[((size_t)bh * L_ + i) * DV_ + tid] = o * inv;
    }
}

extern "C" void kernel_launch(void* const* d_in, const int* in_sizes, int n_in,
                              void* d_out, int out_size, void* d_ws, size_t ws_size,
                              hipStream_t stream) {
    const float* q   = (const float*)d_in[0];
    const float* k   = (const float*)d_in[1];
    const float* v   = (const float*)d_in[2];
    const float* a_k = (const float*)d_in[3];

    float* out  = (float*)d_out;
    float* attn = out + (size_t)B_ * H_ * L_ * DV_;   // out first, attn second

    score_kernel<<<dim3(L_), dim3(256), 0, stream>>>(q, k, a_k, attn);
    finish_kernel<<<dim3(BH_ * L_), dim3(256), 0, stream>>>(v, attn, out);
}

// Round 3
// 536.747 us; speedup vs baseline: 1.8119x; 1.8119x over previous
//
#include <hip/hip_runtime.h>
#include <cstddef>

// Problem constants (fixed by setup_inputs)
#define B_  4
#define L_  1024
#define H_  8
#define DK_ 32
#define DV_ 32
#define BH_ 32            // B_*H_
#define HD_ 256           // H_*DK_

#define INV_T 0.17677669529663687f  // 1/sqrt(32)

// ---------------------------------------------------------------------------
// Kernel 0: transpose q[b, j, h*32+d] -> qT[bh][d][j]  (so j is contiguous)
// grid 128 = bh(32) x jt(4), 256 threads
// ---------------------------------------------------------------------------
__global__ __launch_bounds__(256) void transpose_q(
    const float* __restrict__ q, float* __restrict__ qT)
{
    const int bh  = blockIdx.x >> 2;
    const int jt  = blockIdx.x & 3;
    const int b   = bh >> 3, h = bh & 7;
    const int tid = threadIdx.x;

    __shared__ float t_s[256][33];   // pad 33: out-read banks (tid+d)%32 -> 2-way

    const float* qb = q + (size_t)b * L_ * HD_ + h * DK_;
    #pragma unroll
    for (int rep = 0; rep < 8; ++rep) {
        const int f = rep * 1024 + tid * 4;
        const int j = f >> 5, d = f & 31;
        float4 val = *reinterpret_cast<const float4*>(qb + (size_t)(jt * 256 + j) * HD_ + d);
        t_s[j][d + 0] = val.x; t_s[j][d + 1] = val.y;
        t_s[j][d + 2] = val.z; t_s[j][d + 3] = val.w;
    }
    __syncthreads();
    float* qo = qT + (size_t)bh * (DK_ * L_) + jt * 256;
    #pragma unroll
    for (int d = 0; d < 32; ++d)
        qo[(size_t)d * L_ + tid] = t_s[tid][d];   // coalesced store, 2-way LDS read
}

// ---------------------------------------------------------------------------
// Kernel 1: scores. grid 512 = ig(256: 4 i's each) x half(2: 16 bh each).
// 256 threads = 4 waves; wave w handles bh = half*16 + w*4 .. +3; lane = j.
// Writes u = exp(score/T) (unnormalized) + per-row sums to ws.
// ---------------------------------------------------------------------------
__global__ __launch_bounds__(256) void score_kernel(
    const float* __restrict__ qT,
    const float* __restrict__ k,
    const float* __restrict__ a_k,
    float* __restrict__ attn_u,
    float* __restrict__ sums)
{
    const int ig   = blockIdx.x >> 1;
    const int half = blockIdx.x & 1;
    const int i0   = ig * 4;
    const int bh0  = half * 16;
    const int tid  = threadIdx.x;
    const int w    = tid >> 6;
    const int lane = tid & 63;

    __shared__ float a_s[4][64][36];   // [ii][jj][d] pad 36 (16B-aligned rows)
    __shared__ float k_s[16][4][32];   // [bhl][ii][d] uniform-read (broadcast)

    // stage k_s once
    #pragma unroll
    for (int rep = 0; rep < 2; ++rep) {
        const int f   = rep * 1024 + tid * 4;
        const int bhl = f >> 7, ii = (f >> 5) & 3, d = f & 31;
        const int bh = bh0 + bhl, b = bh >> 3, h = bh & 7;
        float4 val = *reinterpret_cast<const float4*>(
            k + (size_t)b * L_ * HD_ + (size_t)(i0 + ii) * HD_ + h * DK_ + d);
        *reinterpret_cast<float4*>(&k_s[bhl][ii][d]) = val;
    }

    float rs[4][4] = {{0.f}};

    #pragma unroll 1
    for (int jt = 0; jt < 16; ++jt) {
        const int j0 = jt * 64;
        __syncthreads();   // previous tile's readers done
        #pragma unroll
        for (int rep = 0; rep < 8; ++rep) {
            const int f  = rep * 1024 + tid * 4;
            const int ii = f >> 11, jj = (f >> 5) & 63, d = f & 31;
            float4 val = *reinterpret_cast<const float4*>(
                a_k + (size_t)(i0 + ii) * (L_ * DK_) + (size_t)(j0 + jj) * DK_ + d);
            *reinterpret_cast<float4*>(&a_s[ii][jj][d]) = val;
        }
        __syncthreads();

        float s[4][4] = {{0.f}};
        for (int d4 = 0; d4 < 8; ++d4) {
            // register-cache a across the bh loop (4x reuse -> VALU-bound)
            float4 av[4];
            #pragma unroll
            for (int ii = 0; ii < 4; ++ii)
                av[ii] = *reinterpret_cast<const float4*>(&a_s[ii][lane][d4 * 4]);
            #pragma unroll
            for (int bhl = 0; bhl < 4; ++bhl) {
                const int klx = w * 4 + bhl;
                const int bh  = bh0 + klx;
                const float* qp = qT + (size_t)bh * (DK_ * L_) + (size_t)(d4 * 4) * L_ + j0 + lane;
                const float q0 = qp[0];
                const float q1 = qp[L_];
                const float q2 = qp[2 * L_];
                const float q3 = qp[3 * L_];
                #pragma unroll
                for (int ii = 0; ii < 4; ++ii) {
                    float4 kv = *reinterpret_cast<const float4*>(&k_s[klx][ii][d4 * 4]);
                    s[bhl][ii] = fmaf(kv.x * av[ii].x, q0, s[bhl][ii]);
                    s[bhl][ii] = fmaf(kv.y * av[ii].y, q1, s[bhl][ii]);
                    s[bhl][ii] = fmaf(kv.z * av[ii].z, q2, s[bhl][ii]);
                    s[bhl][ii] = fmaf(kv.w * av[ii].w, q3, s[bhl][ii]);
                }
            }
        }

        #pragma unroll
        for (int bhl = 0; bhl < 4; ++bhl) {
            const int bh = bh0 + w * 4 + bhl;
            #pragma unroll
            for (int ii = 0; ii < 4; ++ii) {
                const float u = __expf(s[bhl][ii] * INV_T);
                rs[bhl][ii] += u;
                attn_u[((size_t)bh * L_ + (i0 + ii)) * L_ + j0 + lane] = u;
            }
        }
    }

    // per-row sums: full-wave reduce, lane 0 writes
    #pragma unroll
    for (int bhl = 0; bhl < 4; ++bhl) {
        #pragma unroll
        for (int ii = 0; ii < 4; ++ii) {
            float vsum = rs[bhl][ii];
            #pragma unroll
            for (int off = 32; off > 0; off >>= 1) vsum += __shfl_xor(vsum, off);
            if (lane == 0)
                sums[(size_t)(bh0 + w * 4 + bhl) * L_ + i0 + ii] = vsum;
        }
    }
}

// ---------------------------------------------------------------------------
// Kernel 2: normalize + PV. grid 1024 = bh(32) x ic(32: 32 i-rows each).
// 256 threads: r = tid>>3 (row 0..31), t8 = tid&7 (j-slice for staging,
// dv-quarter for PV). Single pass: inv known from sums.
// ---------------------------------------------------------------------------
__global__ __launch_bounds__(256) void pv_kernel(
    const float* __restrict__ v,
    const float* __restrict__ sums,
    float* __restrict__ attn,    // u on entry, p on exit
    float* __restrict__ out)
{
    const int bh  = blockIdx.x >> 5;
    const int ic  = blockIdx.x & 31;
    const int i0  = ic * 32;
    const int b   = bh >> 3, h = bh & 7;
    const int tid = threadIdx.x;
    const int r   = tid >> 3;
    const int t8  = tid & 7;

    __shared__ float v_s[64][36];    // [jj][dv] pad 36
    __shared__ float u_s[32][64];    // normalized p, broadcast reads

    const float inv = 1.0f / sums[(size_t)bh * L_ + i0 + r];
    float* arow = attn + ((size_t)bh * L_ + i0 + r) * L_;
    const int jj0 = t8 * 8;

    float ax = 0.f, ay = 0.f, az = 0.f, aw = 0.f;

    #pragma unroll 1
    for (int jt = 0; jt < 16; ++jt) {
        const int j0 = jt * 64;
        __syncthreads();   // previous tile's PV readers done
        {   // stage v tile
            const int jj = tid >> 2, dv = (tid & 3) * 8;
            const float* vp = v + (size_t)b * L_ * HD_ + (size_t)(j0 + jj) * HD_ + h * DV_ + dv;
            float4 v0 = *reinterpret_cast<const float4*>(vp);
            float4 v1 = *reinterpret_cast<const float4*>(vp + 4);
            *reinterpret_cast<float4*>(&v_s[jj][dv])     = v0;
            *reinterpret_cast<float4*>(&v_s[jj][dv + 4]) = v1;
        }
        {   // stage u tile normalized; write p back (coalesced)
            float4 u0 = *reinterpret_cast<const float4*>(arow + j0 + jj0);
            float4 u1 = *reinterpret_cast<const float4*>(arow + j0 + jj0 + 4);
            u0.x *= inv; u0.y *= inv; u0.z *= inv; u0.w *= inv;
            u1.x *= inv; u1.y *= inv; u1.z *= inv; u1.w *= inv;
            *reinterpret_cast<float4*>(&u_s[r][jj0])     = u0;
            *reinterpret_cast<float4*>(&u_s[r][jj0 + 4]) = u1;
            *reinterpret_cast<float4*>(arow + j0 + jj0)     = u0;
            *reinterpret_cast<float4*>(arow + j0 + jj0 + 4) = u1;
        }
        __syncthreads();
        // PV: acc[dv-quarter] += p[r][jj] * v[jj][dv]
        #pragma unroll
        for (int jj = 0; jj < 64; ++jj) {
            const float ub = u_s[r][jj];                       // broadcast
            float4 vv = *reinterpret_cast<const float4*>(&v_s[jj][t8 * 4]);
            ax = fmaf(ub, vv.x, ax); ay = fmaf(ub, vv.y, ay);
            az = fmaf(ub, vv.z, az); aw = fmaf(ub, vv.w, aw);
        }
    }
    *reinterpret_cast<float4*>(out + ((size_t)bh * L_ + i0 + r) * DV_ + t8 * 4)
        = make_float4(ax, ay, az, aw);
}

extern "C" void kernel_launch(void* const* d_in, const int* in_sizes, int n_in,
                              void* d_out, int out_size, void* d_ws, size_t ws_size,
                              hipStream_t stream) {
    const float* q   = (const float*)d_in[0];
    const float* k   = (const float*)d_in[1];
    const float* v   = (const float*)d_in[2];
    const float* a_k = (const float*)d_in[3];

    float* out  = (float*)d_out;
    float* attn = out + (size_t)BH_ * L_ * DV_;   // out first, attn second

    float* ws   = (float*)d_ws;
    float* sums = ws;                  // 32*1024 floats = 128 KB
    float* qT   = ws + BH_ * L_;       // 32*32*1024 floats = 4 MB

    transpose_q<<<dim3(128),  dim3(256), 0, stream>>>(q, qT);
    score_kernel<<<dim3(512), dim3(256), 0, stream>>>(qT, k, a_k, attn, sums);
    pv_kernel<<<dim3(1024),   dim3(256), 0, stream>>>(v, sums, attn, out);
}

// Round 4
// 412.371 us; speedup vs baseline: 2.3584x; 1.3016x over previous
//
#include <hip/hip_runtime.h>
#include <cstddef>

// Problem constants (fixed by setup_inputs)
#define B_  4
#define L_  1024
#define H_  8
#define DK_ 32
#define DV_ 32
#define BH_ 32            // B_*H_
#define HD_ 256           // H_*DK_

#define INV_T 0.17677669529663687f  // 1/sqrt(32)

// ---------------------------------------------------------------------------
// Kernel 0: transpose q[b, j, h*32+d] -> qT[bh][d][j]  (so j is contiguous)
// grid 128 = bh(32) x jt(4), 256 threads
// ---------------------------------------------------------------------------
__global__ __launch_bounds__(256) void transpose_q(
    const float* __restrict__ q, float* __restrict__ qT)
{
    const int bh  = blockIdx.x >> 2;
    const int jt  = blockIdx.x & 3;
    const int b   = bh >> 3, h = bh & 7;
    const int tid = threadIdx.x;

    __shared__ float t_s[256][33];

    const float* qb = q + (size_t)b * L_ * HD_ + h * DK_;
    #pragma unroll
    for (int rep = 0; rep < 8; ++rep) {
        const int f = rep * 1024 + tid * 4;
        const int j = f >> 5, d = f & 31;
        float4 val = *reinterpret_cast<const float4*>(qb + (size_t)(jt * 256 + j) * HD_ + d);
        t_s[j][d + 0] = val.x; t_s[j][d + 1] = val.y;
        t_s[j][d + 2] = val.z; t_s[j][d + 3] = val.w;
    }
    __syncthreads();
    float* qo = qT + (size_t)bh * (DK_ * L_) + jt * 256;
    #pragma unroll
    for (int d = 0; d < 32; ++d)
        qo[(size_t)d * L_ + tid] = t_s[tid][d];
}

// ---------------------------------------------------------------------------
// Kernel 1: scores. grid 1024 = ig(256) x half(2) x jhalf(2).
// Block: 4 i's x 16 bh x 512 j's. 256 thr = 4 waves; wave w -> bh w*4..w*4+3.
// k is wave-uniform -> scalar loads (SGPR broadcast), no k LDS.
// Writes u = exp(score/T) + per-row partial sums (per jhalf).
// ---------------------------------------------------------------------------
__global__ __launch_bounds__(256) void score_kernel(
    const float* __restrict__ qT,
    const float* __restrict__ k,
    const float* __restrict__ a_k,
    float* __restrict__ attn_u,
    float* __restrict__ sums)   // [2][BH_][L_] partials
{
    const int bidx  = blockIdx.x;
    const int jhalf = bidx & 1;
    const int half  = (bidx >> 1) & 1;
    const int ig    = bidx >> 2;
    const int i0    = ig * 4;
    const int bh0   = half * 16;
    const int tid   = threadIdx.x;
    const int w     = __builtin_amdgcn_readfirstlane(tid >> 6);  // force wave-uniform
    const int lane  = tid & 63;

    __shared__ float a_s[4][64][36];   // [ii][jj][d] pad 36 (b128 conflict-free)

    float rs[4][4] = {{0.f}};          // [bhl][ii] row-sum partials

    for (int jt = jhalf * 8; jt < jhalf * 8 + 8; ++jt) {
        const int j0 = jt * 64;
        __syncthreads();
        #pragma unroll
        for (int rep = 0; rep < 8; ++rep) {
            const int f  = rep * 1024 + tid * 4;
            const int ii = f >> 11, jj = (f >> 5) & 63, d = f & 31;
            float4 val = *reinterpret_cast<const float4*>(
                a_k + (size_t)(i0 + ii) * (L_ * DK_) + (size_t)(j0 + jj) * DK_ + d);
            *reinterpret_cast<float4*>(&a_s[ii][jj][d]) = val;
        }
        __syncthreads();

        float s[4][4];
        #pragma unroll
        for (int bhl = 0; bhl < 4; ++bhl)
            #pragma unroll
            for (int ii = 0; ii < 4; ++ii) s[bhl][ii] = 0.f;

        #pragma unroll 2
        for (int d4 = 0; d4 < 8; ++d4) {
            float4 av[4];
            #pragma unroll
            for (int ii = 0; ii < 4; ++ii)
                av[ii] = *reinterpret_cast<const float4*>(&a_s[ii][lane][d4 * 4]);
            #pragma unroll
            for (int bhl = 0; bhl < 4; ++bhl) {
                const int bh = bh0 + w * 4 + bhl;      // wave-uniform
                const int b  = bh >> 3, h = bh & 7;
                const float* qp = qT + (size_t)bh * (DK_ * L_) + (size_t)(d4 * 4) * L_ + j0 + lane;
                const float q0 = qp[0];
                const float q1 = qp[L_];
                const float q2 = qp[2 * L_];
                const float q3 = qp[3 * L_];
                const float* kp = k + (size_t)b * L_ * HD_ + (size_t)i0 * HD_ + h * DK_ + d4 * 4;
                #pragma unroll
                for (int ii = 0; ii < 4; ++ii) {
                    float4 kv = *reinterpret_cast<const float4*>(kp + ii * HD_);  // s_load
                    s[bhl][ii] = fmaf(kv.x * av[ii].x, q0, s[bhl][ii]);
                    s[bhl][ii] = fmaf(kv.y * av[ii].y, q1, s[bhl][ii]);
                    s[bhl][ii] = fmaf(kv.z * av[ii].z, q2, s[bhl][ii]);
                    s[bhl][ii] = fmaf(kv.w * av[ii].w, q3, s[bhl][ii]);
                }
            }
        }

        #pragma unroll
        for (int bhl = 0; bhl < 4; ++bhl) {
            const int bh = bh0 + w * 4 + bhl;
            #pragma unroll
            for (int ii = 0; ii < 4; ++ii) {
                const float u = __expf(s[bhl][ii] * INV_T);
                rs[bhl][ii] += u;
                attn_u[((size_t)bh * L_ + (i0 + ii)) * L_ + j0 + lane] = u;
            }
        }
    }

    #pragma unroll
    for (int bhl = 0; bhl < 4; ++bhl) {
        #pragma unroll
        for (int ii = 0; ii < 4; ++ii) {
            float vsum = rs[bhl][ii];
            #pragma unroll
            for (int off = 32; off > 0; off >>= 1) vsum += __shfl_xor(vsum, off);
            if (lane == 0)
                sums[((size_t)jhalf * BH_ + bh0 + w * 4 + bhl) * L_ + i0 + ii] = vsum;
        }
    }
}

// ---------------------------------------------------------------------------
// Kernel 2: normalize + PV. grid 2048 = bh(32) x ic(64: 16 i-rows each).
// 256 thr: r = tid>>4 (row 0..15), t16 = tid&15.
// ---------------------------------------------------------------------------
__global__ __launch_bounds__(256) void pv_kernel(
    const float* __restrict__ v,
    const float* __restrict__ sums,
    float* __restrict__ attn,    // u on entry, p on exit
    float* __restrict__ out)
{
    const int bh  = blockIdx.x >> 6;
    const int ic  = blockIdx.x & 63;
    const int i0  = ic * 16;
    const int b   = bh >> 3, h = bh & 7;
    const int tid = threadIdx.x;
    const int r   = tid >> 4;
    const int t16 = tid & 15;

    __shared__ float v_s[64][36];    // [jj][dv] pad 36
    __shared__ float u_s[16][68];    // pad 68: broadcast reads conflict-free

    const float inv = 1.0f / (sums[(size_t)bh * L_ + i0 + r] +
                              sums[(size_t)(BH_ + bh) * L_ + i0 + r]);
    float* arow = attn + ((size_t)bh * L_ + i0 + r) * L_;

    float a0 = 0.f, a1 = 0.f;

    for (int jt = 0; jt < 16; ++jt) {
        const int j0 = jt * 64;
        __syncthreads();
        {   // stage v tile (64 x 32)
            const int jj = tid >> 2, dv = (tid & 3) * 8;
            const float* vp = v + (size_t)b * L_ * HD_ + (size_t)(j0 + jj) * HD_ + h * DV_ + dv;
            float4 v0 = *reinterpret_cast<const float4*>(vp);
            float4 v1 = *reinterpret_cast<const float4*>(vp + 4);
            *reinterpret_cast<float4*>(&v_s[jj][dv])     = v0;
            *reinterpret_cast<float4*>(&v_s[jj][dv + 4]) = v1;
        }
        {   // stage u tile normalized; write p back
            float4 u0 = *reinterpret_cast<const float4*>(arow + j0 + t16 * 4);
            u0.x *= inv; u0.y *= inv; u0.z *= inv; u0.w *= inv;
            *reinterpret_cast<float4*>(&u_s[r][t16 * 4]) = u0;
            *reinterpret_cast<float4*>(arow + j0 + t16 * 4) = u0;
        }
        __syncthreads();
        // acc[dv pair] += p[r][jj] * v[jj][dv]
        #pragma unroll
        for (int jj = 0; jj < 64; ++jj) {
            const float ub = u_s[r][jj];                          // broadcast
            const float2 vv = *reinterpret_cast<const float2*>(&v_s[jj][t16 * 2]);
            a0 = fmaf(ub, vv.x, a0);
            a1 = fmaf(ub, vv.y, a1);
        }
    }
    *reinterpret_cast<float2*>(out + ((size_t)bh * L_ + i0 + r) * DV_ + t16 * 2)
        = make_float2(a0, a1);
}

extern "C" void kernel_launch(void* const* d_in, const int* in_sizes, int n_in,
                              void* d_out, int out_size, void* d_ws, size_t ws_size,
                              hipStream_t stream) {
    const float* q   = (const float*)d_in[0];
    const float* k   = (const float*)d_in[1];
    const float* v   = (const float*)d_in[2];
    const float* a_k = (const float*)d_in[3];

    float* out  = (float*)d_out;
    float* attn = out + (size_t)BH_ * L_ * DV_;   // out first, attn second

    float* ws   = (float*)d_ws;
    float* sums = ws;                        // 2*32*1024 floats = 256 KB
    float* qT   = ws + 2 * BH_ * L_;         // 4 MB

    transpose_q<<<dim3(128),   dim3(256), 0, stream>>>(q, qT);
    score_kernel<<<dim3(1024), dim3(256), 0, stream>>>(qT, k, a_k, attn, sums);
    pv_kernel<<<dim3(2048),    dim3(256), 0, stream>>>(v, sums, attn, out);
}